// Round 6
// baseline (350.703 us; speedup 1.0000x reference)
//
#include <hip/hip_runtime.h>

#define N_NODES 100000
#define N_EDGES 1600000
#define CDIM    128
#define BATCH   50000
#define NLAYERS 3
#define EPS_BN  1e-5f
#define LPAD    136   // LDS row stride in bf16 elems (272 B)

#define NBUCK   512
#define BW      196     // 512*196 = 100352 >= N_NODES
#define EPB     4096    // edges per block in bucket_fill
#define NEB     ((N_EDGES + EPB - 1) / EPB)   // 391
#define EBCAP   3584    // fixed ebuf slots/bucket (mean 3125, sd 56 -> +8 sigma)

#define ECAP    704     // per-block elist LDS cache (mean 512, sd 22.6 -> +8.5 sigma)

// Layer-3 (l==2) only needs dst rows < BATCH (nodes globally dst-sorted).
#define BBLK3   ((BATCH + 31) / 32)

typedef __attribute__((ext_vector_type(8))) short short8;   // 8 bf16
typedef __attribute__((ext_vector_type(4))) float floatx4;  // MFMA acc
typedef __attribute__((ext_vector_type(2))) float floatx2;  // v_pk_* pair

__device__ __forceinline__ unsigned short f2bf(float f) {
    unsigned int u = __float_as_uint(f);
    u = u + 0x7FFFu + ((u >> 16) & 1u);   // RTNE
    return (unsigned short)(u >> 16);
}
__device__ __forceinline__ unsigned int pk2(float lo, float hi) {
    return (unsigned int)f2bf(lo) | ((unsigned int)f2bf(hi) << 16);
}

// fp8(e4m3) helpers: HW cvt, 2 elems/inst.
__device__ __forceinline__ floatx2 fp8x2_lo(unsigned int u) {
    return __builtin_amdgcn_cvt_pk_f32_fp8((int)u, false);
}
__device__ __forceinline__ floatx2 fp8x2_hi(unsigned int u) {
    return __builtin_amdgcn_cvt_pk_f32_fp8((int)u, true);
}
__device__ __forceinline__ unsigned int f32x4_to_fp8(float f0, float f1, float f2, float f3) {
    int w = __builtin_amdgcn_cvt_pk_fp8_f32(f0, f1, 0, false);
    w = __builtin_amdgcn_cvt_pk_fp8_f32(f2, f3, w, true);
    return (unsigned int)w;
}

// fp8 accumulate: 8 channels (uint2) per edge, packed-f32 adds/fmas.
__device__ __forceinline__ void acc8(uint2 u, floatx2& a01, floatx2& a23,
                                     floatx2& a45, floatx2& a67) {
    a01 = a01 + fp8x2_lo(u.x);
    a23 = a23 + fp8x2_hi(u.x);
    a45 = a45 + fp8x2_lo(u.y);
    a67 = a67 + fp8x2_hi(u.y);
}
__device__ __forceinline__ void acc8w(uint2 u, float w, floatx2& a01, floatx2& a23,
                                      floatx2& a45, floatx2& a67) {
    floatx2 wv; wv.x = w; wv.y = w;
    a01 = fp8x2_lo(u.x) * wv + a01;
    a23 = fp8x2_hi(u.x) * wv + a23;
    a45 = fp8x2_lo(u.y) * wv + a45;
    a67 = fp8x2_hi(u.y) * wv + a67;
}

// Workspace float-offsets.
// CRITICAL (R11): hb0/hb1 bases MUST be 256-B aligned.
// R18: fp8 gather copy (FETCH 186->93 MB, dur 74->64). R19: explicit 2-deep
// pipeline NEUTRAL -> not per-thread-ILP-bound.
// R20 (this round): occupancy attack — drop sH (self rows read from global in
// the MFMA loop; same bytes, L2-hot), LDS 20.4->12.5 KB, launch_bounds(256,8)
// (64-VGPR cap; using 36-40). Decisive A/B: dur drop => concurrency-limited;
// flat => request-rate wall. ALSO: head fused into sage L3 (saves hb0
// write + re-read + a dispatch).
#define OFF_HB0   6400000
#define OFF_HB1   12800000
#define OFF_SC    19200000
#define OFF_RP    19201152   // rowptr, N+1 ints
#define OFF_BCNT  19301184   // 512 (count, fixed-region cursor)
#define OFF_ELIST 19302752   // E ints (exact, contiguous)
#define OFF_EBUF  20902752   // 512*3584 packed uints
#define OFF_WCAT  22737760   // 3*128*256 bf16
#define OFF_WH1   22786912   // 128*128 bf16
#define OFF_WH2   22795104   // 64*128 bf16
// fp8 gather copies (128 B/row, 128-B aligned bases)
#define OFF_XQ    22800000
#define OFF_HQ0   26000000
#define OFF_HQ1   29200000

// ---------------------------------------------------------------------------
// Mega setup+fill kernel + xq fp8 write in the x branch.
// ---------------------------------------------------------------------------
#define XBLK 12500
#define WBLK 384
#define HBLK 96
#define SETUP_BLKS (XBLK + WBLK + HBLK + 1)
__global__ __launch_bounds__(256) void setup_fill(
        const float* __restrict__ x,
        const float* __restrict__ Wl, const float* __restrict__ Wr,
        const float* __restrict__ cW1, const float* __restrict__ cW2,
        const float* __restrict__ g, const float* __restrict__ b,
        const float* __restrict__ m, const float* __restrict__ v,
        const float* __restrict__ cg1, const float* __restrict__ cbe1,
        const float* __restrict__ cm1, const float* __restrict__ cv1,
        const float* __restrict__ cg2, const float* __restrict__ cbe2,
        const float* __restrict__ cm2, const float* __restrict__ cv2,
        const int* __restrict__ ei,
        int* __restrict__ bcnt,
        unsigned int* __restrict__ ebuf,
        float* __restrict__ ws) {
    __shared__ unsigned int st[EPB];      // 16 KB (fill blocks only)
    __shared__ unsigned short sb[EPB];    // 8 KB
    __shared__ int lh[NBUCK];
    __shared__ int gb[NBUCK];
    __shared__ int lc[NBUCK];

    int blk = blockIdx.x;
    int tid = threadIdx.x;
    unsigned short* xb = (unsigned short*)ws;

    if (blk < XBLK) {
        int i = blk * 256 + tid;
        float4 vv = ((const float4*)x)[i];
        ushort4 o;
        o.x = f2bf(vv.x); o.y = f2bf(vv.y); o.z = f2bf(vv.z); o.w = f2bf(vv.w);
        ((ushort4*)xb)[i] = o;
        unsigned int* xq = (unsigned int*)(ws + OFF_XQ);
        xq[i] = f32x4_to_fp8(vv.x, vv.y, vv.z, vv.w);
        return;
    }
    if (blk < XBLK + WBLK) {
        unsigned short* wcat = (unsigned short*)(ws + OFF_WCAT);
        int i = (blk - XBLK) * 256 + tid;
        int l = i >> 15;
        int n = (i >> 8) & 127;
        int k = i & 255;
        float w = (k < CDIM) ? Wl[((size_t)l * CDIM + k) * CDIM + n]
                             : Wr[((size_t)l * CDIM + (k - CDIM)) * CDIM + n];
        wcat[i] = f2bf(w);
        return;
    }
    if (blk < XBLK + WBLK + HBLK) {
        unsigned short* wh1 = (unsigned short*)(ws + OFF_WH1);
        unsigned short* wh2 = (unsigned short*)(ws + OFF_WH2);
        int i = (blk - XBLK - WBLK) * 256 + tid;
        if (i < 128 * 128) {
            int n = i >> 7, k = i & 127;
            wh1[i] = f2bf(cW1[k * 128 + n]);
        } else if (i < 128 * 128 + 64 * 128) {
            int j = i - 128 * 128;
            int n = j >> 7, k = j & 127;
            wh2[j] = f2bf(cW2[k * 64 + n]);
        }
        return;
    }
    if (blk == XBLK + WBLK + HBLK) {
        float* sc = ws + OFF_SC;
        for (int i = tid; i < NLAYERS * CDIM; i += 256) {
            float s = g[i] * rsqrtf(v[i] + EPS_BN);
            sc[i] = s;
            sc[NLAYERS * CDIM + i] = b[i] - m[i] * s;
        }
        if (tid < CDIM) {
            float s = cg1[tid] * rsqrtf(cv1[tid] + EPS_BN);
            sc[768 + tid] = s;
            sc[896 + tid] = cbe1[tid] - cm1[tid] * s;
        }
        if (tid < 64) {
            float s = cg2[tid] * rsqrtf(cv2[tid] + EPS_BN);
            sc[1024 + tid] = s;
            sc[1088 + tid] = cbe2[tid] - cm2[tid] * s;
        }
        return;
    }

    // ----- bucket_fill body -----
    int fb = blk - SETUP_BLKS;
    for (int t = tid; t < NBUCK; t += 256) { lh[t] = 0; lc[t] = 0; }
    __syncthreads();
    int base = fb * EPB;
    int cnt = min(EPB, N_EDGES - base);    // always multiple of 4
    for (int k = tid; k < cnt / 4; k += 256) {
        int4 s4 = ((const int4*)(ei + base))[k];
        int4 d4 = ((const int4*)(ei + N_EDGES + base))[k];
        int i0 = k * 4;
#pragma unroll
        for (int q = 0; q < 4; ++q) {
            int s = (q == 0) ? s4.x : (q == 1) ? s4.y : (q == 2) ? s4.z : s4.w;
            int d = (q == 0) ? d4.x : (q == 1) ? d4.y : (q == 2) ? d4.z : d4.w;
            int bk = (unsigned)d / BW;
            int ld = d - bk * BW;
            st[i0 + q] = (unsigned)s | ((unsigned)ld << 17);
            sb[i0 + q] = (unsigned short)bk;
            atomicAdd(&lh[bk], 1);
        }
    }
    __syncthreads();
    for (int t = tid; t < NBUCK; t += 256) {
        int c = lh[t];
        gb[t] = c ? (t * EBCAP + atomicAdd(&bcnt[t], c)) : 0;
    }
    __syncthreads();
    for (int i = tid; i < cnt; i += 256) {
        int bk = sb[i];
        int pos = gb[bk] + atomicAdd(&lc[bk], 1);
        ebuf[pos] = st[i];
    }
}

// ---------------------------------------------------------------------------
// bucket_csr (unchanged)
// ---------------------------------------------------------------------------
__global__ __launch_bounds__(256) void bucket_csr(const unsigned int* __restrict__ ebuf,
                                                  const int* __restrict__ bcnt,
                                                  int* __restrict__ elist,
                                                  int* __restrict__ rowptr) {
    __shared__ int sbb[NBUCK];
    __shared__ unsigned int st[EBCAP];
    __shared__ int out[EBCAP];
    __shared__ int h[256], sscan[256], pre[256], cur[256];
    int b = blockIdx.x;
    int tid = threadIdx.x;
    int cnt = min(bcnt[b], EBCAP);

    sbb[tid] = bcnt[tid];
    sbb[tid + 256] = bcnt[tid + 256];
    h[tid] = 0; cur[tid] = 0;
    __syncthreads();
    for (int off = 1; off < NBUCK; off <<= 1) {
        int v0 = (tid >= off) ? sbb[tid - off] : 0;
        int t2 = tid + 256;
        int v1 = sbb[t2 - off];
        __syncthreads();
        sbb[tid] += v0;
        sbb[t2] += v1;
        __syncthreads();
    }
    int obase = (b == 0) ? 0 : sbb[b - 1];

    int ebase = b * EBCAP;
    for (int i = tid; i < cnt; i += 256) {
        unsigned int u = ebuf[ebase + i];
        st[i] = u;
        atomicAdd(&h[u >> 17], 1);
    }
    __syncthreads();
    sscan[tid] = h[tid];
    __syncthreads();
    for (int off = 1; off < 256; off <<= 1) {
        int v = (tid >= off) ? sscan[tid - off] : 0;
        __syncthreads();
        sscan[tid] += v;
        __syncthreads();
    }
    pre[tid] = sscan[tid] - h[tid];
    __syncthreads();
    for (int i = tid; i < cnt; i += 256) {
        unsigned int u = st[i];
        int ld = u >> 17;
        int pos = pre[ld] + atomicAdd(&cur[ld], 1);
        out[pos] = (int)(u & 0x1FFFFu);
    }
    __syncthreads();
    for (int i = tid; i < cnt; i += 256) elist[obase + i] = out[i];
    int gn = b * BW + tid;
    if (tid < BW && gn < N_NODES) rowptr[gn] = obase + pre[tid];
    if (b == 0 && tid == 0) rowptr[N_NODES] = N_EDGES;
}

// ---------------------------------------------------------------------------
// Fused SAGE layer — R20: no sH (self rows from global in MFMA loop),
// launch_bounds(256,8), R4-style predicated gather, optional fused MLP head
// (out != nullptr => layer 3: consume BN output in-LDS, write out[] only).
// ---------------------------------------------------------------------------
__global__ __launch_bounds__(256, 8) void sage_fused(const int* __restrict__ rowptr,
                                                     const int* __restrict__ elist,
                                                     const unsigned short* __restrict__ hin,
                                                     const unsigned char* __restrict__ hinq,
                                                     unsigned short* __restrict__ hout,
                                                     unsigned char* __restrict__ houtq,
                                                     int wq,
                                                     const unsigned short* __restrict__ wcat,
                                                     const float* __restrict__ bl,
                                                     const float* __restrict__ scale,
                                                     const float* __restrict__ shift,
                                                     const unsigned short* __restrict__ wh1,
                                                     const unsigned short* __restrict__ wh2,
                                                     const float* __restrict__ cb1,
                                                     const float* __restrict__ s1,
                                                     const float* __restrict__ t1,
                                                     const float* __restrict__ cb2,
                                                     const float* __restrict__ s2,
                                                     const float* __restrict__ t2,
                                                     const float* __restrict__ W3,
                                                     const float* __restrict__ b3,
                                                     float* __restrict__ out) {
    __shared__ unsigned short sA[32][LPAD];
    __shared__ int selist[ECAP + 8];   // +8 pad (zeroed): tail over-reads safe
    __shared__ int srp[33];
    __shared__ float sP[4][32];
    __shared__ float sw3[64];

    int row0 = blockIdx.x * 32;
    int tid = threadIdx.x;
    int lane = tid & 31;
    int grp = tid >> 5;       // 8 node-groups
    int sub = lane >> 4;      // 0/1: chunk parity
    int li  = lane & 15;      // 16 lanes x 8 channels
    int li8 = li * 8;         // shorts (bf16) / bytes (fp8)

    // --- stage CSR slice ---
    int beg0 = rowptr[row0];
    int end0 = rowptr[row0 + 32];
    int ecnt = min(end0 - beg0, ECAP);
    for (int i = tid; i < ecnt + 8; i += 256)
        selist[i] = (i < ecnt) ? elist[beg0 + i] : 0;
    if (tid < 33) srp[tid] = rowptr[row0 + tid];
    if (out && tid < 64) sw3[tid] = W3[tid];
    __syncthreads();

    for (int rr = 0; rr < 4; ++rr) {
        int r = rr * 8 + grp;
        int beg = srp[r];
        int end = srp[r + 1];
        bool all_cached = (end - beg0) <= ecnt;
        floatx2 a01 = (floatx2)0.f, a23 = (floatx2)0.f,
                a45 = (floatx2)0.f, a67 = (floatx2)0.f;

        for (int j = beg + sub * 8; j < end; j += 16) {
            int lj = j - beg0;
            int s0, s1q, s2q, s3q, s4q, s5q, s6q, s7q;
            if (all_cached || (lj + 8 <= ecnt)) {
                s0  = selist[lj];     s1q = selist[lj + 1];
                s2q = selist[lj + 2]; s3q = selist[lj + 3];
                s4q = selist[lj + 4]; s5q = selist[lj + 5];
                s6q = selist[lj + 6]; s7q = selist[lj + 7];
            } else {               // overflow fallback (8.5-sigma event)
                s0  = elist[j];     s1q = elist[j + 1];
                s2q = elist[j + 2]; s3q = elist[j + 3];
                s4q = elist[j + 4]; s5q = elist[j + 5];
                s6q = elist[j + 6]; s7q = elist[j + 7];
            }
            bool p1 = (j + 1 < end), p2 = (j + 2 < end), p3 = (j + 3 < end),
                 p4 = (j + 4 < end), p5 = (j + 5 < end), p6 = (j + 6 < end),
                 p7 = (j + 7 < end);
            s1q = p1 ? s1q : 0; s2q = p2 ? s2q : 0; s3q = p3 ? s3q : 0;
            s4q = p4 ? s4q : 0; s5q = p5 ? s5q : 0; s6q = p6 ? s6q : 0;
            s7q = p7 ? s7q : 0;
            uint2 u0 = *((const uint2*)(hinq + (unsigned)((s0  << 7) + li8)));
            uint2 u1 = *((const uint2*)(hinq + (unsigned)((s1q << 7) + li8)));
            uint2 u2 = *((const uint2*)(hinq + (unsigned)((s2q << 7) + li8)));
            uint2 u3 = *((const uint2*)(hinq + (unsigned)((s3q << 7) + li8)));
            uint2 u4 = *((const uint2*)(hinq + (unsigned)((s4q << 7) + li8)));
            uint2 u5 = *((const uint2*)(hinq + (unsigned)((s5q << 7) + li8)));
            uint2 u6 = *((const uint2*)(hinq + (unsigned)((s6q << 7) + li8)));
            uint2 u7 = *((const uint2*)(hinq + (unsigned)((s7q << 7) + li8)));
            acc8(u0, a01, a23, a45, a67);
            acc8w(u1, p1 ? 1.f : 0.f, a01, a23, a45, a67);
            acc8w(u2, p2 ? 1.f : 0.f, a01, a23, a45, a67);
            acc8w(u3, p3 ? 1.f : 0.f, a01, a23, a45, a67);
            acc8w(u4, p4 ? 1.f : 0.f, a01, a23, a45, a67);
            acc8w(u5, p5 ? 1.f : 0.f, a01, a23, a45, a67);
            acc8w(u6, p6 ? 1.f : 0.f, a01, a23, a45, a67);
            acc8w(u7, p7 ? 1.f : 0.f, a01, a23, a45, a67);
        }

        float a0 = a01.x, a1 = a01.y, a2 = a23.x, a3 = a23.y,
              a4 = a45.x, a5 = a45.y, a6 = a67.x, a7 = a67.y;
        a0 += __shfl_xor(a0, 16); a1 += __shfl_xor(a1, 16);
        a2 += __shfl_xor(a2, 16); a3 += __shfl_xor(a3, 16);
        a4 += __shfl_xor(a4, 16); a5 += __shfl_xor(a5, 16);
        a6 += __shfl_xor(a6, 16); a7 += __shfl_xor(a7, 16);
        if (sub == 0) {
            float rin = 1.0f / fmaxf((float)(end - beg), 1.0f);
            uint4 o;
            o.x = pk2(a0 * rin, a1 * rin);
            o.y = pk2(a2 * rin, a3 * rin);
            o.z = pk2(a4 * rin, a5 * rin);
            o.w = pk2(a6 * rin, a7 * rin);
            *((uint4*)&sA[r][li8]) = o;
        }
    }
    __syncthreads();

    int wave = tid >> 6;
    int wl   = tid & 63;
    int ln16 = wl & 15;
    int quad = wl >> 4;

    floatx4 acc[2][2];
#pragma unroll
    for (int mt = 0; mt < 2; ++mt)
#pragma unroll
        for (int nt = 0; nt < 2; ++nt) acc[mt][nt] = (floatx4)0.0f;

    const unsigned short* wbase = wcat + ((size_t)(wave * 32 + ln16) * 256 + quad * 8);
    const unsigned short* hr0 = hin + (size_t)(row0 + ln16) * CDIM;
    const unsigned short* hr1 = hin + (size_t)(row0 + 16 + ln16) * CDIM;

#pragma unroll
    for (int kb = 0; kb < 4; ++kb) {      // K 0..127: aggregated rows (LDS)
        int koff = kb * 32 + quad * 8;
        short8 a0 = *((const short8*)(&sA[ln16][koff]));
        short8 a1 = *((const short8*)(&sA[ln16 + 16][koff]));
        short8 b0 = *((const short8*)(wbase + kb * 32));
        short8 b1 = *((const short8*)(wbase + 16 * 256 + kb * 32));
        acc[0][0] = __builtin_amdgcn_mfma_f32_16x16x32_bf16(a0, b0, acc[0][0], 0, 0, 0);
        acc[1][0] = __builtin_amdgcn_mfma_f32_16x16x32_bf16(a1, b0, acc[1][0], 0, 0, 0);
        acc[0][1] = __builtin_amdgcn_mfma_f32_16x16x32_bf16(a0, b1, acc[0][1], 0, 0, 0);
        acc[1][1] = __builtin_amdgcn_mfma_f32_16x16x32_bf16(a1, b1, acc[1][1], 0, 0, 0);
    }
#pragma unroll
    for (int kb = 4; kb < 8; ++kb) {      // K 128..255: self rows (global, L2-hot)
        int koff = (kb - 4) * 32 + quad * 8;
        short8 a0 = *((const short8*)(hr0 + koff));
        short8 a1 = *((const short8*)(hr1 + koff));
        short8 b0 = *((const short8*)(wbase + kb * 32));
        short8 b1 = *((const short8*)(wbase + 16 * 256 + kb * 32));
        acc[0][0] = __builtin_amdgcn_mfma_f32_16x16x32_bf16(a0, b0, acc[0][0], 0, 0, 0);
        acc[1][0] = __builtin_amdgcn_mfma_f32_16x16x32_bf16(a1, b0, acc[1][0], 0, 0, 0);
        acc[0][1] = __builtin_amdgcn_mfma_f32_16x16x32_bf16(a0, b1, acc[0][1], 0, 0, 0);
        acc[1][1] = __builtin_amdgcn_mfma_f32_16x16x32_bf16(a1, b1, acc[1][1], 0, 0, 0);
    }

    __syncthreads();
#pragma unroll
    for (int nt = 0; nt < 2; ++nt) {
        int col = wave * 32 + nt * 16 + ln16;
        float bb = bl[col];
        float ss = scale[col];
        float tt = shift[col];
#pragma unroll
        for (int mt = 0; mt < 2; ++mt) {
#pragma unroll
            for (int r = 0; r < 4; ++r) {
                float v = fmaxf(acc[mt][nt][r] + bb, 0.0f) * ss + tt;
                sA[mt * 16 + quad * 4 + r][col] = f2bf(v);
            }
        }
    }
    __syncthreads();

    if (!out) {
        // L1/L2: write bf16 + fp8 copies
#pragma unroll
        for (int it = 0; it < 2; ++it) {
            int idx = it * 256 + tid;
            int r = idx >> 4;
            int c = idx & 15;
            uint4 u = *((const uint4*)&sA[r][c * 8]);
            *((uint4*)(hout + (size_t)(row0 + r) * CDIM + c * 8)) = u;
            if (wq) {
                float f0 = __uint_as_float(u.x << 16), f1 = __uint_as_float(u.x & 0xFFFF0000u);
                float f2 = __uint_as_float(u.y << 16), f3 = __uint_as_float(u.y & 0xFFFF0000u);
                float f4 = __uint_as_float(u.z << 16), f5 = __uint_as_float(u.z & 0xFFFF0000u);
                float f6 = __uint_as_float(u.w << 16), f7 = __uint_as_float(u.w & 0xFFFF0000u);
                uint2 q;
                q.x = f32x4_to_fp8(f0, f1, f2, f3);
                q.y = f32x4_to_fp8(f4, f5, f6, f7);
                *((uint2*)(houtq + (size_t)(row0 + r) * 128 + c * 8)) = q;
            }
        }
        return;
    }

    // ---- fused MLP head (layer 3 only): sA holds 32 BN rows ----
    floatx4 h1[2][2];
#pragma unroll
    for (int mt = 0; mt < 2; ++mt) { h1[mt][0] = (floatx4)0.0f; h1[mt][1] = (floatx4)0.0f; }
    const unsigned short* w1a = wh1 + (size_t)(wave * 32 + ln16) * 128 + quad * 8;
    const unsigned short* w1b = w1a + 16 * 128;
#pragma unroll
    for (int kb = 0; kb < 4; ++kb) {
        int koff = kb * 32 + quad * 8;
        short8 b0 = *((const short8*)(w1a + kb * 32));
        short8 b1 = *((const short8*)(w1b + kb * 32));
#pragma unroll
        for (int mt = 0; mt < 2; ++mt) {
            short8 af = *((const short8*)(&sA[mt * 16 + ln16][koff]));
            h1[mt][0] = __builtin_amdgcn_mfma_f32_16x16x32_bf16(af, b0, h1[mt][0], 0, 0, 0);
            h1[mt][1] = __builtin_amdgcn_mfma_f32_16x16x32_bf16(af, b1, h1[mt][1], 0, 0, 0);
        }
    }
    __syncthreads();
#pragma unroll
    for (int nt = 0; nt < 2; ++nt) {
        int col = wave * 32 + nt * 16 + ln16;
        float bb = cb1[col], ss = s1[col], tt = t1[col];
#pragma unroll
        for (int mt = 0; mt < 2; ++mt) {
#pragma unroll
            for (int r = 0; r < 4; ++r) {
                float v = fmaxf((h1[mt][nt][r] + bb) * ss + tt, 0.0f);
                sA[mt * 16 + quad * 4 + r][col] = f2bf(v);
            }
        }
    }
    __syncthreads();

    floatx4 h2[2];
    h2[0] = (floatx4)0.0f; h2[1] = (floatx4)0.0f;
    const unsigned short* w2a = wh2 + (size_t)(wave * 16 + ln16) * 128 + quad * 8;
#pragma unroll
    for (int kb = 0; kb < 4; ++kb) {
        int koff = kb * 32 + quad * 8;
        short8 b0 = *((const short8*)(w2a + kb * 32));
#pragma unroll
        for (int mt = 0; mt < 2; ++mt) {
            short8 af = *((const short8*)(&sA[mt * 16 + ln16][koff]));
            h2[mt] = __builtin_amdgcn_mfma_f32_16x16x32_bf16(af, b0, h2[mt], 0, 0, 0);
        }
    }
    {
        int col = wave * 16 + ln16;
        float bb = cb2[col], ss = s2[col], tt = t2[col];
        float w3v = sw3[col];
#pragma unroll
        for (int mt = 0; mt < 2; ++mt) {
#pragma unroll
            for (int r = 0; r < 4; ++r) {
                float v = fmaxf((h2[mt][r] + bb) * ss + tt, 0.0f) * w3v;
                v += __shfl_xor(v, 1);
                v += __shfl_xor(v, 2);
                v += __shfl_xor(v, 4);
                v += __shfl_xor(v, 8);
                if (ln16 == 0) sP[wave][mt * 16 + quad * 4 + r] = v;
            }
        }
    }
    __syncthreads();
    if (tid < 32) {
        int row = row0 + tid;
        if (row < BATCH)
            out[row] = sP[0][tid] + sP[1][tid] + sP[2][tid] + sP[3][tid] + b3[0];
    }
}

// ---------------------------------------------------------------------------
extern "C" void kernel_launch(void* const* d_in, const int* in_sizes, int n_in,
                              void* d_out, int out_size, void* d_ws, size_t ws_size,
                              hipStream_t stream) {
    const float* x    = (const float*)d_in[0];
    const int*   ei   = (const int*)d_in[1];
    const float* Wl   = (const float*)d_in[3];
    const float* bl   = (const float*)d_in[4];
    const float* Wr   = (const float*)d_in[5];
    const float* bn_g = (const float*)d_in[6];
    const float* bn_b = (const float*)d_in[7];
    const float* bn_m = (const float*)d_in[8];
    const float* bn_v = (const float*)d_in[9];
    const float* cW1  = (const float*)d_in[10];
    const float* cb1  = (const float*)d_in[11];
    const float* cg1  = (const float*)d_in[12];
    const float* cbe1 = (const float*)d_in[13];
    const float* cm1  = (const float*)d_in[14];
    const float* cv1  = (const float*)d_in[15];
    const float* cW2  = (const float*)d_in[16];
    const float* cb2  = (const float*)d_in[17];
    const float* cg2  = (const float*)d_in[18];
    const float* cbe2 = (const float*)d_in[19];
    const float* cm2  = (const float*)d_in[20];
    const float* cv2  = (const float*)d_in[21];
    const float* cW3  = (const float*)d_in[22];
    const float* cb3  = (const float*)d_in[23];

    float* ws  = (float*)d_ws;
    unsigned short* xb  = (unsigned short*)ws;
    unsigned short* hb0 = (unsigned short*)(ws + OFF_HB0);
    unsigned short* hb1 = (unsigned short*)(ws + OFF_HB1);
    float* sc    = ws + OFF_SC;
    int* rowptr  = (int*)(ws + OFF_RP);
    int* bcnt    = (int*)(ws + OFF_BCNT);
    int* elist   = (int*)(ws + OFF_ELIST);
    unsigned int* ebuf = (unsigned int*)(ws + OFF_EBUF);
    unsigned short* wcat = (unsigned short*)(ws + OFF_WCAT);
    unsigned short* wh1  = (unsigned short*)(ws + OFF_WH1);
    unsigned short* wh2  = (unsigned short*)(ws + OFF_WH2);
    unsigned char* xq  = (unsigned char*)(ws + OFF_XQ);
    unsigned char* hq0 = (unsigned char*)(ws + OFF_HQ0);
    unsigned char* hq1 = (unsigned char*)(ws + OFF_HQ1);

    hipMemsetAsync(bcnt, 0, NBUCK * sizeof(int), stream);

    setup_fill<<<SETUP_BLKS + NEB, 256, 0, stream>>>(
        x, Wl, Wr, cW1, cW2,
        bn_g, bn_b, bn_m, bn_v,
        cg1, cbe1, cm1, cv1,
        cg2, cbe2, cm2, cv2,
        ei, bcnt, ebuf, ws);

    bucket_csr<<<NBUCK, 256, 0, stream>>>(ebuf, bcnt, elist, rowptr);

    // L1, L2: plain layers (write bf16 + fp8 copies)
    sage_fused<<<N_NODES / 32, 256, 0, stream>>>(
        rowptr, elist, xb, xq, hb0, hq0, 1,
        wcat, bl, sc, sc + 384,
        nullptr, nullptr, nullptr, nullptr, nullptr,
        nullptr, nullptr, nullptr, nullptr, nullptr, nullptr);
    sage_fused<<<N_NODES / 32, 256, 0, stream>>>(
        rowptr, elist, hb0, hq0, hb1, hq1, 1,
        wcat + (size_t)CDIM * 256, bl + CDIM, sc + CDIM, sc + 384 + CDIM,
        nullptr, nullptr, nullptr, nullptr, nullptr,
        nullptr, nullptr, nullptr, nullptr, nullptr, nullptr);
    // L3 + fused head: no hout/houtq writes, out[] directly
    sage_fused<<<BBLK3, 256, 0, stream>>>(
        rowptr, elist, hb1, hq1, hb0, hq0, 0,
        wcat + (size_t)2 * CDIM * 256, bl + 2 * CDIM, sc + 2 * CDIM, sc + 384 + 2 * CDIM,
        wh1, wh2,
        cb1, sc + 768, sc + 896,
        cb2, sc + 1024, sc + 1088,
        cW3, cb3, (float*)d_out);
}

// Round 7
// 327.672 us; speedup vs baseline: 1.0703x; 1.0703x over previous
//
#include <hip/hip_runtime.h>

#define N_NODES 100000
#define N_EDGES 1600000
#define CDIM    128
#define BATCH   50000
#define NLAYERS 3
#define EPS_BN  1e-5f
#define LPAD    136   // LDS row stride in bf16 elems (272 B)

#define NBUCK   512
#define BW      196     // 512*196 = 100352 >= N_NODES
#define EPB     4096    // edges per block in bucket_fill
#define NEB     ((N_EDGES + EPB - 1) / EPB)   // 391
#define EBCAP   3584    // fixed ebuf slots/bucket (mean 3125, sd 56 -> +8 sigma)

#define ECAP    704     // per-block elist LDS cache (mean 512, sd 22.6 -> +8.5 sigma)

// Layer-3 (l==2) only needs dst rows < BATCH (nodes globally dst-sorted).
#define BBLK3   ((BATCH + 31) / 32)

typedef __attribute__((ext_vector_type(8))) short short8;   // 8 bf16
typedef __attribute__((ext_vector_type(4))) float floatx4;  // MFMA acc
typedef __attribute__((ext_vector_type(2))) float floatx2;  // v_pk_* pair

__device__ __forceinline__ unsigned short f2bf(float f) {
    unsigned int u = __float_as_uint(f);
    u = u + 0x7FFFu + ((u >> 16) & 1u);   // RTNE
    return (unsigned short)(u >> 16);
}
__device__ __forceinline__ unsigned int pk2(float lo, float hi) {
    return (unsigned int)f2bf(lo) | ((unsigned int)f2bf(hi) << 16);
}

// fp8(e4m3) helpers: HW cvt, 2 elems/inst.
__device__ __forceinline__ floatx2 fp8x2_lo(unsigned int u) {
    return __builtin_amdgcn_cvt_pk_f32_fp8((int)u, false);
}
__device__ __forceinline__ floatx2 fp8x2_hi(unsigned int u) {
    return __builtin_amdgcn_cvt_pk_f32_fp8((int)u, true);
}
__device__ __forceinline__ unsigned int f32x4_to_fp8(float f0, float f1, float f2, float f3) {
    int w = __builtin_amdgcn_cvt_pk_fp8_f32(f0, f1, 0, false);
    w = __builtin_amdgcn_cvt_pk_fp8_f32(f2, f3, w, true);
    return (unsigned int)w;
}

// fp8 accumulate: 8 channels (uint2) per edge, packed-f32 adds/fmas.
__device__ __forceinline__ void acc8(uint2 u, floatx2& a01, floatx2& a23,
                                     floatx2& a45, floatx2& a67) {
    a01 = a01 + fp8x2_lo(u.x);
    a23 = a23 + fp8x2_hi(u.x);
    a45 = a45 + fp8x2_lo(u.y);
    a67 = a67 + fp8x2_hi(u.y);
}
__device__ __forceinline__ void acc8w(uint2 u, float w, floatx2& a01, floatx2& a23,
                                      floatx2& a45, floatx2& a67) {
    floatx2 wv; wv.x = w; wv.y = w;
    a01 = fp8x2_lo(u.x) * wv + a01;
    a23 = fp8x2_hi(u.x) * wv + a23;
    a45 = fp8x2_lo(u.y) * wv + a45;
    a67 = fp8x2_hi(u.y) * wv + a67;
}

// Workspace float-offsets.
// CRITICAL (R11): hb0/hb1 bases MUST be 256-B aligned.
// R18 (proven best sage, 64.2 us): fp8 gather + sH LDS-staged self rows +
// (256,6). R19 (ILP pipeline) NEUTRAL. R20 (drop sH, (256,8)) REGRESSED:
// +12% occupancy bought nothing — gather is at a request-service wall —
// and the uncoalesced global self-row MFMA reads cost ~9 us. LESSON: keep
// sH; self-row MFMA operands must be coalesced-staged.
// R21 (this round): R18 sage body verbatim + R20's (numerically validated)
// L3 head fusion only.
#define OFF_HB0   6400000
#define OFF_HB1   12800000
#define OFF_SC    19200000
#define OFF_RP    19201152   // rowptr, N+1 ints
#define OFF_BCNT  19301184   // 512 (count, fixed-region cursor)
#define OFF_ELIST 19302752   // E ints (exact, contiguous)
#define OFF_EBUF  20902752   // 512*3584 packed uints
#define OFF_WCAT  22737760   // 3*128*256 bf16
#define OFF_WH1   22786912   // 128*128 bf16
#define OFF_WH2   22795104   // 64*128 bf16
// fp8 gather copies (128 B/row, 128-B aligned bases)
#define OFF_XQ    22800000
#define OFF_HQ0   26000000
#define OFF_HQ1   29200000

// ---------------------------------------------------------------------------
// Mega setup+fill kernel + xq fp8 write in the x branch.
// ---------------------------------------------------------------------------
#define XBLK 12500
#define WBLK 384
#define HBLK 96
#define SETUP_BLKS (XBLK + WBLK + HBLK + 1)
__global__ __launch_bounds__(256) void setup_fill(
        const float* __restrict__ x,
        const float* __restrict__ Wl, const float* __restrict__ Wr,
        const float* __restrict__ cW1, const float* __restrict__ cW2,
        const float* __restrict__ g, const float* __restrict__ b,
        const float* __restrict__ m, const float* __restrict__ v,
        const float* __restrict__ cg1, const float* __restrict__ cbe1,
        const float* __restrict__ cm1, const float* __restrict__ cv1,
        const float* __restrict__ cg2, const float* __restrict__ cbe2,
        const float* __restrict__ cm2, const float* __restrict__ cv2,
        const int* __restrict__ ei,
        int* __restrict__ bcnt,
        unsigned int* __restrict__ ebuf,
        float* __restrict__ ws) {
    __shared__ unsigned int st[EPB];      // 16 KB (fill blocks only)
    __shared__ unsigned short sb[EPB];    // 8 KB
    __shared__ int lh[NBUCK];
    __shared__ int gb[NBUCK];
    __shared__ int lc[NBUCK];

    int blk = blockIdx.x;
    int tid = threadIdx.x;
    unsigned short* xb = (unsigned short*)ws;

    if (blk < XBLK) {
        int i = blk * 256 + tid;
        float4 vv = ((const float4*)x)[i];
        ushort4 o;
        o.x = f2bf(vv.x); o.y = f2bf(vv.y); o.z = f2bf(vv.z); o.w = f2bf(vv.w);
        ((ushort4*)xb)[i] = o;
        unsigned int* xq = (unsigned int*)(ws + OFF_XQ);
        xq[i] = f32x4_to_fp8(vv.x, vv.y, vv.z, vv.w);
        return;
    }
    if (blk < XBLK + WBLK) {
        unsigned short* wcat = (unsigned short*)(ws + OFF_WCAT);
        int i = (blk - XBLK) * 256 + tid;
        int l = i >> 15;
        int n = (i >> 8) & 127;
        int k = i & 255;
        float w = (k < CDIM) ? Wl[((size_t)l * CDIM + k) * CDIM + n]
                             : Wr[((size_t)l * CDIM + (k - CDIM)) * CDIM + n];
        wcat[i] = f2bf(w);
        return;
    }
    if (blk < XBLK + WBLK + HBLK) {
        unsigned short* wh1 = (unsigned short*)(ws + OFF_WH1);
        unsigned short* wh2 = (unsigned short*)(ws + OFF_WH2);
        int i = (blk - XBLK - WBLK) * 256 + tid;
        if (i < 128 * 128) {
            int n = i >> 7, k = i & 127;
            wh1[i] = f2bf(cW1[k * 128 + n]);
        } else if (i < 128 * 128 + 64 * 128) {
            int j = i - 128 * 128;
            int n = j >> 7, k = j & 127;
            wh2[j] = f2bf(cW2[k * 64 + n]);
        }
        return;
    }
    if (blk == XBLK + WBLK + HBLK) {
        float* sc = ws + OFF_SC;
        for (int i = tid; i < NLAYERS * CDIM; i += 256) {
            float s = g[i] * rsqrtf(v[i] + EPS_BN);
            sc[i] = s;
            sc[NLAYERS * CDIM + i] = b[i] - m[i] * s;
        }
        if (tid < CDIM) {
            float s = cg1[tid] * rsqrtf(cv1[tid] + EPS_BN);
            sc[768 + tid] = s;
            sc[896 + tid] = cbe1[tid] - cm1[tid] * s;
        }
        if (tid < 64) {
            float s = cg2[tid] * rsqrtf(cv2[tid] + EPS_BN);
            sc[1024 + tid] = s;
            sc[1088 + tid] = cbe2[tid] - cm2[tid] * s;
        }
        return;
    }

    // ----- bucket_fill body -----
    int fb = blk - SETUP_BLKS;
    for (int t = tid; t < NBUCK; t += 256) { lh[t] = 0; lc[t] = 0; }
    __syncthreads();
    int base = fb * EPB;
    int cnt = min(EPB, N_EDGES - base);    // always multiple of 4
    for (int k = tid; k < cnt / 4; k += 256) {
        int4 s4 = ((const int4*)(ei + base))[k];
        int4 d4 = ((const int4*)(ei + N_EDGES + base))[k];
        int i0 = k * 4;
#pragma unroll
        for (int q = 0; q < 4; ++q) {
            int s = (q == 0) ? s4.x : (q == 1) ? s4.y : (q == 2) ? s4.z : s4.w;
            int d = (q == 0) ? d4.x : (q == 1) ? d4.y : (q == 2) ? d4.z : d4.w;
            int bk = (unsigned)d / BW;
            int ld = d - bk * BW;
            st[i0 + q] = (unsigned)s | ((unsigned)ld << 17);
            sb[i0 + q] = (unsigned short)bk;
            atomicAdd(&lh[bk], 1);
        }
    }
    __syncthreads();
    for (int t = tid; t < NBUCK; t += 256) {
        int c = lh[t];
        gb[t] = c ? (t * EBCAP + atomicAdd(&bcnt[t], c)) : 0;
    }
    __syncthreads();
    for (int i = tid; i < cnt; i += 256) {
        int bk = sb[i];
        int pos = gb[bk] + atomicAdd(&lc[bk], 1);
        ebuf[pos] = st[i];
    }
}

// ---------------------------------------------------------------------------
// bucket_csr (unchanged)
// ---------------------------------------------------------------------------
__global__ __launch_bounds__(256) void bucket_csr(const unsigned int* __restrict__ ebuf,
                                                  const int* __restrict__ bcnt,
                                                  int* __restrict__ elist,
                                                  int* __restrict__ rowptr) {
    __shared__ int sbb[NBUCK];
    __shared__ unsigned int st[EBCAP];
    __shared__ int out[EBCAP];
    __shared__ int h[256], sscan[256], pre[256], cur[256];
    int b = blockIdx.x;
    int tid = threadIdx.x;
    int cnt = min(bcnt[b], EBCAP);

    sbb[tid] = bcnt[tid];
    sbb[tid + 256] = bcnt[tid + 256];
    h[tid] = 0; cur[tid] = 0;
    __syncthreads();
    for (int off = 1; off < NBUCK; off <<= 1) {
        int v0 = (tid >= off) ? sbb[tid - off] : 0;
        int t2 = tid + 256;
        int v1 = sbb[t2 - off];
        __syncthreads();
        sbb[tid] += v0;
        sbb[t2] += v1;
        __syncthreads();
    }
    int obase = (b == 0) ? 0 : sbb[b - 1];

    int ebase = b * EBCAP;
    for (int i = tid; i < cnt; i += 256) {
        unsigned int u = ebuf[ebase + i];
        st[i] = u;
        atomicAdd(&h[u >> 17], 1);
    }
    __syncthreads();
    sscan[tid] = h[tid];
    __syncthreads();
    for (int off = 1; off < 256; off <<= 1) {
        int v = (tid >= off) ? sscan[tid - off] : 0;
        __syncthreads();
        sscan[tid] += v;
        __syncthreads();
    }
    pre[tid] = sscan[tid] - h[tid];
    __syncthreads();
    for (int i = tid; i < cnt; i += 256) {
        unsigned int u = st[i];
        int ld = u >> 17;
        int pos = pre[ld] + atomicAdd(&cur[ld], 1);
        out[pos] = (int)(u & 0x1FFFFu);
    }
    __syncthreads();
    for (int i = tid; i < cnt; i += 256) elist[obase + i] = out[i];
    int gn = b * BW + tid;
    if (tid < BW && gn < N_NODES) rowptr[gn] = obase + pre[tid];
    if (b == 0 && tid == 0) rowptr[N_NODES] = N_EDGES;
}

// ---------------------------------------------------------------------------
// Fused SAGE layer — R21: R18 body (fp8 gather, sH staged, (256,6)) +
// optional fused MLP head (out != nullptr => layer 3).
// ---------------------------------------------------------------------------
__global__ __launch_bounds__(256, 6) void sage_fused(const int* __restrict__ rowptr,
                                                     const int* __restrict__ elist,
                                                     const unsigned short* __restrict__ hin,
                                                     const unsigned char* __restrict__ hinq,
                                                     unsigned short* __restrict__ hout,
                                                     unsigned char* __restrict__ houtq,
                                                     int wq,
                                                     const unsigned short* __restrict__ wcat,
                                                     const float* __restrict__ bl,
                                                     const float* __restrict__ scale,
                                                     const float* __restrict__ shift,
                                                     const unsigned short* __restrict__ wh1,
                                                     const unsigned short* __restrict__ wh2,
                                                     const float* __restrict__ cb1,
                                                     const float* __restrict__ s1,
                                                     const float* __restrict__ t1,
                                                     const float* __restrict__ cb2,
                                                     const float* __restrict__ s2,
                                                     const float* __restrict__ t2,
                                                     const float* __restrict__ W3,
                                                     const float* __restrict__ b3,
                                                     float* __restrict__ out) {
    __shared__ unsigned short sA[32][LPAD];
    __shared__ unsigned short sH[32][LPAD];
    __shared__ int selist[ECAP + 8];   // +8 pad (zeroed): tail over-reads safe
    __shared__ int srp[33];
    __shared__ float sP[4][32];
    __shared__ float sw3[64];

    int row0 = blockIdx.x * 32;
    int tid = threadIdx.x;
    int lane = tid & 31;
    int grp = tid >> 5;       // 8 node-groups
    int sub = lane >> 4;      // 0/1: chunk parity
    int li  = lane & 15;      // 16 lanes x 8 channels
    int li8 = li * 8;         // shorts (bf16) / bytes (fp8)

    // --- stage CSR slice + own rows ---
    int beg0 = rowptr[row0];
    int end0 = rowptr[row0 + 32];
    int ecnt = min(end0 - beg0, ECAP);
    for (int i = tid; i < ecnt + 8; i += 256)
        selist[i] = (i < ecnt) ? elist[beg0 + i] : 0;
    if (tid < 33) srp[tid] = rowptr[row0 + tid];
    if (out && tid < 64) sw3[tid] = W3[tid];
    for (int it = 0; it < 4; ++it) {
        int idx = it * 256 + tid;
        int r = idx >> 5;
        int c4 = idx & 31;
        uint2 u = ((const uint2*)(hin + (size_t)(row0 + r) * CDIM))[c4];
        *((uint2*)&sH[r][c4 * 4]) = u;
    }
    __syncthreads();

    for (int rr = 0; rr < 4; ++rr) {
        int r = rr * 8 + grp;
        int beg = srp[r];
        int end = srp[r + 1];
        bool all_cached = (end - beg0) <= ecnt;
        floatx2 a01 = (floatx2)0.f, a23 = (floatx2)0.f,
                a45 = (floatx2)0.f, a67 = (floatx2)0.f;

        for (int j = beg + sub * 8; j < end; j += 16) {
            int lj = j - beg0;
            int s0, s1q, s2q, s3q, s4q, s5q, s6q, s7q;
            if (all_cached || (lj + 8 <= ecnt)) {
                s0  = selist[lj];     s1q = selist[lj + 1];
                s2q = selist[lj + 2]; s3q = selist[lj + 3];
                s4q = selist[lj + 4]; s5q = selist[lj + 5];
                s6q = selist[lj + 6]; s7q = selist[lj + 7];
            } else {               // overflow fallback (8.5-sigma event)
                s0  = elist[j];     s1q = elist[j + 1];
                s2q = elist[j + 2]; s3q = elist[j + 3];
                s4q = elist[j + 4]; s5q = elist[j + 5];
                s6q = elist[j + 6]; s7q = elist[j + 7];
            }
            bool p1 = (j + 1 < end), p2 = (j + 2 < end), p3 = (j + 3 < end),
                 p4 = (j + 4 < end), p5 = (j + 5 < end), p6 = (j + 6 < end),
                 p7 = (j + 7 < end);
            s1q = p1 ? s1q : 0; s2q = p2 ? s2q : 0; s3q = p3 ? s3q : 0;
            s4q = p4 ? s4q : 0; s5q = p5 ? s5q : 0; s6q = p6 ? s6q : 0;
            s7q = p7 ? s7q : 0;
            uint2 u0 = *((const uint2*)(hinq + (unsigned)((s0  << 7) + li8)));
            uint2 u1 = *((const uint2*)(hinq + (unsigned)((s1q << 7) + li8)));
            uint2 u2 = *((const uint2*)(hinq + (unsigned)((s2q << 7) + li8)));
            uint2 u3 = *((const uint2*)(hinq + (unsigned)((s3q << 7) + li8)));
            uint2 u4 = *((const uint2*)(hinq + (unsigned)((s4q << 7) + li8)));
            uint2 u5 = *((const uint2*)(hinq + (unsigned)((s5q << 7) + li8)));
            uint2 u6 = *((const uint2*)(hinq + (unsigned)((s6q << 7) + li8)));
            uint2 u7 = *((const uint2*)(hinq + (unsigned)((s7q << 7) + li8)));
            acc8(u0, a01, a23, a45, a67);
            acc8w(u1, p1 ? 1.f : 0.f, a01, a23, a45, a67);
            acc8w(u2, p2 ? 1.f : 0.f, a01, a23, a45, a67);
            acc8w(u3, p3 ? 1.f : 0.f, a01, a23, a45, a67);
            acc8w(u4, p4 ? 1.f : 0.f, a01, a23, a45, a67);
            acc8w(u5, p5 ? 1.f : 0.f, a01, a23, a45, a67);
            acc8w(u6, p6 ? 1.f : 0.f, a01, a23, a45, a67);
            acc8w(u7, p7 ? 1.f : 0.f, a01, a23, a45, a67);
        }

        float a0 = a01.x, a1 = a01.y, a2 = a23.x, a3 = a23.y,
              a4 = a45.x, a5 = a45.y, a6 = a67.x, a7 = a67.y;
        a0 += __shfl_xor(a0, 16); a1 += __shfl_xor(a1, 16);
        a2 += __shfl_xor(a2, 16); a3 += __shfl_xor(a3, 16);
        a4 += __shfl_xor(a4, 16); a5 += __shfl_xor(a5, 16);
        a6 += __shfl_xor(a6, 16); a7 += __shfl_xor(a7, 16);
        if (sub == 0) {
            float rin = 1.0f / fmaxf((float)(end - beg), 1.0f);
            uint4 o;
            o.x = pk2(a0 * rin, a1 * rin);
            o.y = pk2(a2 * rin, a3 * rin);
            o.z = pk2(a4 * rin, a5 * rin);
            o.w = pk2(a6 * rin, a7 * rin);
            *((uint4*)&sA[r][li8]) = o;
        }
    }
    __syncthreads();

    int wave = tid >> 6;
    int wl   = tid & 63;
    int ln16 = wl & 15;
    int quad = wl >> 4;

    floatx4 acc[2][2];
#pragma unroll
    for (int mt = 0; mt < 2; ++mt)
#pragma unroll
        for (int nt = 0; nt < 2; ++nt) acc[mt][nt] = (floatx4)0.0f;

    const unsigned short* wbase = wcat + ((size_t)(wave * 32 + ln16) * 256 + quad * 8);

#pragma unroll
    for (int kb = 0; kb < 8; ++kb) {
        int koff = (kb & 3) * 32 + quad * 8;
        const unsigned short* sbuf = (kb < 4) ? &sA[0][0] : &sH[0][0];
        short8 a0 = *((const short8*)(sbuf + (ln16)      * LPAD + koff));
        short8 a1 = *((const short8*)(sbuf + (ln16 + 16) * LPAD + koff));
        short8 b0 = *((const short8*)(wbase + kb * 32));
        short8 b1 = *((const short8*)(wbase + 16 * 256 + kb * 32));
        acc[0][0] = __builtin_amdgcn_mfma_f32_16x16x32_bf16(a0, b0, acc[0][0], 0, 0, 0);
        acc[1][0] = __builtin_amdgcn_mfma_f32_16x16x32_bf16(a1, b0, acc[1][0], 0, 0, 0);
        acc[0][1] = __builtin_amdgcn_mfma_f32_16x16x32_bf16(a0, b1, acc[0][1], 0, 0, 0);
        acc[1][1] = __builtin_amdgcn_mfma_f32_16x16x32_bf16(a1, b1, acc[1][1], 0, 0, 0);
    }

    __syncthreads();
#pragma unroll
    for (int nt = 0; nt < 2; ++nt) {
        int col = wave * 32 + nt * 16 + ln16;
        float bb = bl[col];
        float ss = scale[col];
        float tt = shift[col];
#pragma unroll
        for (int mt = 0; mt < 2; ++mt) {
#pragma unroll
            for (int r = 0; r < 4; ++r) {
                float v = fmaxf(acc[mt][nt][r] + bb, 0.0f) * ss + tt;
                sA[mt * 16 + quad * 4 + r][col] = f2bf(v);
            }
        }
    }
    __syncthreads();

    if (!out) {
        // L1/L2: write bf16 + fp8 copies
#pragma unroll
        for (int it = 0; it < 2; ++it) {
            int idx = it * 256 + tid;
            int r = idx >> 4;
            int c = idx & 15;
            uint4 u = *((const uint4*)&sA[r][c * 8]);
            *((uint4*)(hout + (size_t)(row0 + r) * CDIM + c * 8)) = u;
            if (wq) {
                float f0 = __uint_as_float(u.x << 16), f1 = __uint_as_float(u.x & 0xFFFF0000u);
                float f2 = __uint_as_float(u.y << 16), f3 = __uint_as_float(u.y & 0xFFFF0000u);
                float f4 = __uint_as_float(u.z << 16), f5 = __uint_as_float(u.z & 0xFFFF0000u);
                float f6 = __uint_as_float(u.w << 16), f7 = __uint_as_float(u.w & 0xFFFF0000u);
                uint2 q;
                q.x = f32x4_to_fp8(f0, f1, f2, f3);
                q.y = f32x4_to_fp8(f4, f5, f6, f7);
                *((uint2*)(houtq + (size_t)(row0 + r) * 128 + c * 8)) = q;
            }
        }
        return;
    }

    // ---- fused MLP head (layer 3 only): sA holds 32 BN rows ----
    floatx4 h1[2][2];
#pragma unroll
    for (int mt = 0; mt < 2; ++mt) { h1[mt][0] = (floatx4)0.0f; h1[mt][1] = (floatx4)0.0f; }
    const unsigned short* w1a = wh1 + (size_t)(wave * 32 + ln16) * 128 + quad * 8;
    const unsigned short* w1b = w1a + 16 * 128;
#pragma unroll
    for (int kb = 0; kb < 4; ++kb) {
        int koff = kb * 32 + quad * 8;
        short8 b0 = *((const short8*)(w1a + kb * 32));
        short8 b1 = *((const short8*)(w1b + kb * 32));
#pragma unroll
        for (int mt = 0; mt < 2; ++mt) {
            short8 af = *((const short8*)(&sA[mt * 16 + ln16][koff]));
            h1[mt][0] = __builtin_amdgcn_mfma_f32_16x16x32_bf16(af, b0, h1[mt][0], 0, 0, 0);
            h1[mt][1] = __builtin_amdgcn_mfma_f32_16x16x32_bf16(af, b1, h1[mt][1], 0, 0, 0);
        }
    }
    __syncthreads();
#pragma unroll
    for (int nt = 0; nt < 2; ++nt) {
        int col = wave * 32 + nt * 16 + ln16;
        float bb = cb1[col], ss = s1[col], tt = t1[col];
#pragma unroll
        for (int mt = 0; mt < 2; ++mt) {
#pragma unroll
            for (int r = 0; r < 4; ++r) {
                float v = fmaxf((h1[mt][nt][r] + bb) * ss + tt, 0.0f);
                sA[mt * 16 + quad * 4 + r][col] = f2bf(v);
            }
        }
    }
    __syncthreads();

    floatx4 h2[2];
    h2[0] = (floatx4)0.0f; h2[1] = (floatx4)0.0f;
    const unsigned short* w2a = wh2 + (size_t)(wave * 16 + ln16) * 128 + quad * 8;
#pragma unroll
    for (int kb = 0; kb < 4; ++kb) {
        int koff = kb * 32 + quad * 8;
        short8 b0 = *((const short8*)(w2a + kb * 32));
#pragma unroll
        for (int mt = 0; mt < 2; ++mt) {
            short8 af = *((const short8*)(&sA[mt * 16 + ln16][koff]));
            h2[mt] = __builtin_amdgcn_mfma_f32_16x16x32_bf16(af, b0, h2[mt], 0, 0, 0);
        }
    }
    {
        int col = wave * 16 + ln16;
        float bb = cb2[col], ss = s2[col], tt = t2[col];
        float w3v = sw3[col];
#pragma unroll
        for (int mt = 0; mt < 2; ++mt) {
#pragma unroll
            for (int r = 0; r < 4; ++r) {
                float v = fmaxf((h2[mt][r] + bb) * ss + tt, 0.0f) * w3v;
                v += __shfl_xor(v, 1);
                v += __shfl_xor(v, 2);
                v += __shfl_xor(v, 4);
                v += __shfl_xor(v, 8);
                if (ln16 == 0) sP[wave][mt * 16 + quad * 4 + r] = v;
            }
        }
    }
    __syncthreads();
    if (tid < 32) {
        int row = row0 + tid;
        if (row < BATCH)
            out[row] = sP[0][tid] + sP[1][tid] + sP[2][tid] + sP[3][tid] + b3[0];
    }
}

// ---------------------------------------------------------------------------
extern "C" void kernel_launch(void* const* d_in, const int* in_sizes, int n_in,
                              void* d_out, int out_size, void* d_ws, size_t ws_size,
                              hipStream_t stream) {
    const float* x    = (const float*)d_in[0];
    const int*   ei   = (const int*)d_in[1];
    const float* Wl   = (const float*)d_in[3];
    const float* bl   = (const float*)d_in[4];
    const float* Wr   = (const float*)d_in[5];
    const float* bn_g = (const float*)d_in[6];
    const float* bn_b = (const float*)d_in[7];
    const float* bn_m = (const float*)d_in[8];
    const float* bn_v = (const float*)d_in[9];
    const float* cW1  = (const float*)d_in[10];
    const float* cb1  = (const float*)d_in[11];
    const float* cg1  = (const float*)d_in[12];
    const float* cbe1 = (const float*)d_in[13];
    const float* cm1  = (const float*)d_in[14];
    const float* cv1  = (const float*)d_in[15];
    const float* cW2  = (const float*)d_in[16];
    const float* cb2  = (const float*)d_in[17];
    const float* cg2  = (const float*)d_in[18];
    const float* cbe2 = (const float*)d_in[19];
    const float* cm2  = (const float*)d_in[20];
    const float* cv2  = (const float*)d_in[21];
    const float* cW3  = (const float*)d_in[22];
    const float* cb3  = (const float*)d_in[23];

    float* ws  = (float*)d_ws;
    unsigned short* xb  = (unsigned short*)ws;
    unsigned short* hb0 = (unsigned short*)(ws + OFF_HB0);
    unsigned short* hb1 = (unsigned short*)(ws + OFF_HB1);
    float* sc    = ws + OFF_SC;
    int* rowptr  = (int*)(ws + OFF_RP);
    int* bcnt    = (int*)(ws + OFF_BCNT);
    int* elist   = (int*)(ws + OFF_ELIST);
    unsigned int* ebuf = (unsigned int*)(ws + OFF_EBUF);
    unsigned short* wcat = (unsigned short*)(ws + OFF_WCAT);
    unsigned short* wh1  = (unsigned short*)(ws + OFF_WH1);
    unsigned short* wh2  = (unsigned short*)(ws + OFF_WH2);
    unsigned char* xq  = (unsigned char*)(ws + OFF_XQ);
    unsigned char* hq0 = (unsigned char*)(ws + OFF_HQ0);
    unsigned char* hq1 = (unsigned char*)(ws + OFF_HQ1);

    hipMemsetAsync(bcnt, 0, NBUCK * sizeof(int), stream);

    setup_fill<<<SETUP_BLKS + NEB, 256, 0, stream>>>(
        x, Wl, Wr, cW1, cW2,
        bn_g, bn_b, bn_m, bn_v,
        cg1, cbe1, cm1, cv1,
        cg2, cbe2, cm2, cv2,
        ei, bcnt, ebuf, ws);

    bucket_csr<<<NBUCK, 256, 0, stream>>>(ebuf, bcnt, elist, rowptr);

    // L1, L2: plain layers (write bf16 + fp8 copies)
    sage_fused<<<N_NODES / 32, 256, 0, stream>>>(
        rowptr, elist, xb, xq, hb0, hq0, 1,
        wcat, bl, sc, sc + 384,
        nullptr, nullptr, nullptr, nullptr, nullptr,
        nullptr, nullptr, nullptr, nullptr, nullptr, nullptr);
    sage_fused<<<N_NODES / 32, 256, 0, stream>>>(
        rowptr, elist, hb0, hq0, hb1, hq1, 1,
        wcat + (size_t)CDIM * 256, bl + CDIM, sc + CDIM, sc + 384 + CDIM,
        nullptr, nullptr, nullptr, nullptr, nullptr,
        nullptr, nullptr, nullptr, nullptr, nullptr, nullptr);
    // L3 + fused head: no hout/houtq writes, out[] directly
    sage_fused<<<BBLK3, 256, 0, stream>>>(
        rowptr, elist, hb1, hq1, hb0, hq0, 0,
        wcat + (size_t)2 * CDIM * 256, bl + 2 * CDIM, sc + 2 * CDIM, sc + 384 + 2 * CDIM,
        wh1, wh2,
        cb1, sc + 768, sc + 896,
        cb2, sc + 1024, sc + 1088,
        cW3, cb3, (float*)d_out);
}